// Round 3
// baseline (22374.463 us; speedup 1.0000x reference)
//
#include <hip/hip_runtime.h>
#include <cstdint>
#include <cstddef>

#define SEQT  512
#define HID   1024
#define G3    3072

typedef __attribute__((ext_vector_type(8))) short bf16x8;
typedef __attribute__((ext_vector_type(8))) unsigned short u16x8;
typedef __attribute__((ext_vector_type(4))) float f32x4;

__device__ __forceinline__ float sigm(float x){ return 1.0f/(1.0f+expf(-x)); }
__device__ __forceinline__ float b2f(unsigned short s){ return __uint_as_float(((uint32_t)s)<<16); }
__device__ __forceinline__ unsigned short f2b(float f){
    uint32_t u=__float_as_uint(f);
    return (unsigned short)((u + 0x7FFFu + ((u>>16)&1u))>>16);
}

// ---------------------------------------------------------------------------
// MFMA GEMM: C[m][n] = epilogue( sum_k A[m][k]*W[n][k] )
// Tile 128x128, BK=64, 256 thr = 4 waves, each wave 64x64 (4x4 frags 16x16x32).
// ASRC: 0 = bf16 via global_load_lds; 1 = f32 reg-staged (convert);
//       2 = bf16 reg-staged with *(1+gate[m>>9][k]) fused.
// BSRC: 0 = bf16 via global_load_lds; 1 = f32 reg-staged.
// MODE: 0 = f32 out, +bias.  1 = bf16 out, tanh(+bias+ctx[m>>9][n]).
//       2 = bf16 out, +bias.
// ---------------------------------------------------------------------------
template<int ASRC, int BSRC, int MODE>
__global__ __launch_bounds__(256) void mfma_gemm(
    const void* __restrict__ Av, const void* __restrict__ Bv,
    const float* __restrict__ bias, const float* __restrict__ ctx,
    const float* __restrict__ gate, void* __restrict__ Cv,
    int N, int K)
{
    __shared__ __align__(16) unsigned short As[128*64];
    __shared__ __align__(16) unsigned short Bs[128*64];
    const int tid = threadIdx.x;
    const int lane = tid & 63;
    const int w = tid >> 6;
    const int wm = w & 1, wn = w >> 1;
    const int m0 = blockIdx.y * 128, n0 = blockIdx.x * 128;

    f32x4 acc[4][4];
#pragma unroll
    for (int i = 0; i < 4; i++)
#pragma unroll
        for (int j = 0; j < 4; j++) acc[i][j] = (f32x4){0.f,0.f,0.f,0.f};

    for (int kt = 0; kt < K; kt += 64) {
        __syncthreads();
        // ---- stage A tile [128 rows][64 k] -> As linear
        if (ASRC == 0) {
            const unsigned short* Ab = (const unsigned short*)Av;
#pragma unroll
            for (int c = 0; c < 4; c++) {
                const int chunk = w*4 + c;
                const int row = chunk*8 + (lane>>3);
                const unsigned short* src = Ab + (size_t)(m0+row)*K + kt + (lane&7)*8;
                __builtin_amdgcn_global_load_lds(
                    (const __attribute__((address_space(1))) void*)src,
                    (__attribute__((address_space(3))) void*)&As[chunk*512], 16, 0, 0);
            }
        } else if (ASRC == 1) {
            const float* Af = (const float*)Av;
#pragma unroll
            for (int p = 0; p < 4; p++) {
                const int q = p*256 + tid, row = q>>3, kc = q&7;
                const float* src = Af + (size_t)(m0+row)*K + kt + kc*8;
                float4 u = *(const float4*)src, v = *(const float4*)(src+4);
                __align__(16) unsigned short tmp[8] =
                    {f2b(u.x),f2b(u.y),f2b(u.z),f2b(u.w),f2b(v.x),f2b(v.y),f2b(v.z),f2b(v.w)};
                *(bf16x8*)&As[row*64 + kc*8] = *(const bf16x8*)tmp;
            }
        } else {
            const unsigned short* Ab = (const unsigned short*)Av;
#pragma unroll
            for (int p = 0; p < 4; p++) {
                const int q = p*256 + tid, row = q>>3, kc = q&7;
                const int b = (m0+row) >> 9;
                u16x8 hv = *(const u16x8*)(Ab + (size_t)(m0+row)*K + kt + kc*8);
                const float* gp = gate + (size_t)b*HID + kt + kc*8;
                float4 g0 = *(const float4*)gp, g1 = *(const float4*)(gp+4);
                const float gg[8] = {g0.x,g0.y,g0.z,g0.w,g1.x,g1.y,g1.z,g1.w};
                __align__(16) unsigned short tmp[8];
#pragma unroll
                for (int e = 0; e < 8; e++)
                    tmp[e] = f2b(b2f(hv[e]) * (1.0f + gg[e]));
                *(bf16x8*)&As[row*64 + kc*8] = *(const bf16x8*)tmp;
            }
        }
        // ---- stage B tile [128 n-rows][64 k] -> Bs linear
        if (BSRC == 0) {
            const unsigned short* Bb = (const unsigned short*)Bv;
#pragma unroll
            for (int c = 0; c < 4; c++) {
                const int chunk = w*4 + c;
                const int row = chunk*8 + (lane>>3);
                const unsigned short* src = Bb + (size_t)(n0+row)*K + kt + (lane&7)*8;
                __builtin_amdgcn_global_load_lds(
                    (const __attribute__((address_space(1))) void*)src,
                    (__attribute__((address_space(3))) void*)&Bs[chunk*512], 16, 0, 0);
            }
        } else {
            const float* Bf = (const float*)Bv;
#pragma unroll
            for (int p = 0; p < 4; p++) {
                const int q = p*256 + tid, row = q>>3, kc = q&7;
                const float* src = Bf + (size_t)(n0+row)*K + kt + kc*8;
                float4 u = *(const float4*)src, v = *(const float4*)(src+4);
                __align__(16) unsigned short tmp[8] =
                    {f2b(u.x),f2b(u.y),f2b(u.z),f2b(u.w),f2b(v.x),f2b(v.y),f2b(v.z),f2b(v.w)};
                *(bf16x8*)&Bs[row*64 + kc*8] = *(const bf16x8*)tmp;
            }
        }
        __syncthreads();
        // ---- compute: 2 k-groups x 16 mfma
#pragma unroll
        for (int kg = 0; kg < 2; kg++) {
            bf16x8 af[4], bfr[4];
#pragma unroll
            for (int mi = 0; mi < 4; mi++)
                af[mi] = *(const bf16x8*)&As[(wm*64+mi*16+(lane&15))*64 + kg*32 + (lane>>4)*8];
#pragma unroll
            for (int ni = 0; ni < 4; ni++)
                bfr[ni] = *(const bf16x8*)&Bs[(wn*64+ni*16+(lane&15))*64 + kg*32 + (lane>>4)*8];
#pragma unroll
            for (int mi = 0; mi < 4; mi++)
#pragma unroll
                for (int ni = 0; ni < 4; ni++)
                    acc[mi][ni] = __builtin_amdgcn_mfma_f32_16x16x32_bf16(
                        af[mi], bfr[ni], acc[mi][ni], 0, 0, 0);
        }
    }

    // ---- epilogue: D[row=(lane>>4)*4+r][col=lane&15] per frag
    const int cl = lane & 15, rg = lane >> 4;
    const int bct = m0 >> 9;
#pragma unroll
    for (int mi = 0; mi < 4; mi++) {
        const int rowb = m0 + wm*64 + mi*16 + rg*4;
#pragma unroll
        for (int ni = 0; ni < 4; ni++) {
            const int col = n0 + wn*64 + ni*16 + cl;
            const float bv = bias[col];
            const float cv = (MODE==1) ? ctx[(size_t)bct*HID + col] : 0.0f;
#pragma unroll
            for (int r = 0; r < 4; r++) {
                float val = acc[mi][ni][r] + bv;
                if (MODE==1) val = tanhf(val + cv);
                const size_t off = (size_t)(rowb+r)*N + col;
                if (MODE==0) ((float*)Cv)[off] = val;
                else ((unsigned short*)Cv)[off] = f2b(val);
            }
        }
    }
}

// ---------------------------------------------------------------------------
// gate[b][j] = sigmoid( sum_k ctx[b][k] * Wg[j][k] + bg[j] )    (all f32)
// ---------------------------------------------------------------------------
__global__ __launch_bounds__(256) void gate_kernel(
    const float* __restrict__ ctx, const float* __restrict__ Wg,
    const float* __restrict__ bg, float* __restrict__ gate)
{
    const int j = blockIdx.x * 256 + threadIdx.x;
    const int b = blockIdx.y;
    const float4* cp = (const float4*)(ctx + (size_t)b * HID);
    const float4* wp = (const float4*)(Wg + (size_t)j * HID);
    float acc = 0.0f;
#pragma unroll 4
    for (int k = 0; k < HID / 4; k++) {
        float4 c = cp[k], w = wp[k];
        acc += c.x * w.x + c.y * w.y + c.z * w.z + c.w * w.w;
    }
    gate[(size_t)b * HID + j] = sigm(acc + bg[j]);
}

// ---------------------------------------------------------------------------
// f32 -> bf16 elementwise (weight conversion)
// ---------------------------------------------------------------------------
__global__ __launch_bounds__(256) void f2b_kernel(
    const float* __restrict__ in, unsigned short* __restrict__ out, int n)
{
    const int i = (blockIdx.x * 256 + threadIdx.x) * 4;
    if (i < n) {
        float4 v = *(const float4*)(in + i);
        unsigned short s[4] = {f2b(v.x), f2b(v.y), f2b(v.z), f2b(v.w)};
        *(short4*)(out + i) = *(short4*)s;
    }
}

// ---------------------------------------------------------------------------
// Persistent GRU layer scan. 64 blocks x 384 thr (6 waves). Block owns 16 j.
// LDS: Whh slice (48 rows x 1024, bf16, padded 1032) + sc[3][32][17] f32.
// Wave w = (mh = w&1 batch-half, g = w>>2? no: g = w>>1 gate).
// Per step: 32 chained mfma 16x16x32 (4 accs) -> sc -> finalize -> barrier.
// ---------------------------------------------------------------------------
__global__ __launch_bounds__(384, 1) void gru_scan(
    const float* __restrict__ Whh, const float* __restrict__ bhh,
    const unsigned short* __restrict__ xg, unsigned short* __restrict__ hbuf,
    unsigned int* __restrict__ bar, int nblocks)
{
    __shared__ __align__(16) unsigned short wlds[48*1032];
    __shared__ float sc[3][32][17];
    const int tid = threadIdx.x;
    const int lane = tid & 63;
    const int w = tid >> 6;
    const int j0 = blockIdx.x * 16;
    const int mh = w & 1, g = w >> 1;
    const int cl = lane & 15, kq = lane >> 4;

    // stage Whh slice f32 -> bf16 LDS: rows rr = g*16+jr -> Whh[g*1024+j0+jr]
    for (int i = tid; i < 48*128; i += 384) {
        const int rr = i >> 7, kc = i & 127;
        const int grow = (rr>>4)*1024 + j0 + (rr&15);
        const float* src = Whh + (size_t)grow*1024 + kc*8;
        float4 u = *(const float4*)src, v = *(const float4*)(src+4);
        __align__(16) unsigned short tmp[8] =
            {f2b(u.x),f2b(u.y),f2b(u.z),f2b(u.w),f2b(v.x),f2b(v.y),f2b(v.z),f2b(v.w)};
        *(bf16x8*)&wlds[rr*1032 + kc*8] = *(const bf16x8*)tmp;
    }
    __syncthreads();

    const unsigned short* wrow = &wlds[(g*16+cl)*1032 + kq*8];

    for (int t = 0; t < SEQT; t++) {
        f32x4 a0 = {0.f,0.f,0.f,0.f}, a1 = a0, a2 = a0, a3 = a0;
        if (t > 0) {
            const unsigned short* hrow =
                hbuf + ((size_t)(mh*16+cl)*SEQT + (t-1))*HID + kq*8;
#pragma unroll
            for (int kg = 0; kg < 32; kg += 4) {
                bf16x8 h0 = *(const bf16x8*)(hrow + (size_t)(kg+0)*32);
                bf16x8 w0 = *(const bf16x8*)(wrow + (size_t)(kg+0)*32);
                a0 = __builtin_amdgcn_mfma_f32_16x16x32_bf16(h0, w0, a0, 0,0,0);
                bf16x8 h1 = *(const bf16x8*)(hrow + (size_t)(kg+1)*32);
                bf16x8 w1 = *(const bf16x8*)(wrow + (size_t)(kg+1)*32);
                a1 = __builtin_amdgcn_mfma_f32_16x16x32_bf16(h1, w1, a1, 0,0,0);
                bf16x8 h2 = *(const bf16x8*)(hrow + (size_t)(kg+2)*32);
                bf16x8 w2 = *(const bf16x8*)(wrow + (size_t)(kg+2)*32);
                a2 = __builtin_amdgcn_mfma_f32_16x16x32_bf16(h2, w2, a2, 0,0,0);
                bf16x8 h3 = *(const bf16x8*)(hrow + (size_t)(kg+3)*32);
                bf16x8 w3 = *(const bf16x8*)(wrow + (size_t)(kg+3)*32);
                a3 = __builtin_amdgcn_mfma_f32_16x16x32_bf16(h3, w3, a3, 0,0,0);
            }
        }
        f32x4 av = (a0 + a1) + (a2 + a3);
#pragma unroll
        for (int r = 0; r < 4; r++)
            sc[g][mh*16 + kq*4 + r][cl] = av[r];
        __syncthreads();

        if (tid < 256) {
            const int b = tid >> 3, jp = (tid & 7) * 2;
            const size_t mrow = (size_t)b*SEQT + t;
            float hp[2] = {0.f, 0.f};
            if (t > 0) {
                hp[0] = b2f(hbuf[(mrow-1)*HID + j0 + jp]);
                hp[1] = b2f(hbuf[(mrow-1)*HID + j0 + jp + 1]);
            }
            const unsigned short* xp = xg + mrow*G3 + j0 + jp;
#pragma unroll
            for (int e = 0; e < 2; e++) {
                const int j = jp + e, jg = j0 + j;
                const float r = sigm(b2f(xp[e])      + sc[0][b][j] + bhh[jg]);
                const float z = sigm(b2f(xp[1024+e]) + sc[1][b][j] + bhh[HID+jg]);
                const float n = tanhf(b2f(xp[2048+e]) + r*(sc[2][b][j] + bhh[2*HID+jg]));
                const float h = (1.0f - z)*n + z*hp[e];
                hbuf[mrow*HID + jg] = f2b(h);
            }
        }
        __threadfence();
        __syncthreads();
        if (tid == 0) {
            atomicAdd(bar, 1u);
            const unsigned int target = (unsigned int)nblocks * (unsigned int)(t+1);
            while (__hip_atomic_load(bar, __ATOMIC_RELAXED, __HIP_MEMORY_SCOPE_AGENT) < target)
                __builtin_amdgcn_s_sleep(2);
        }
        __syncthreads();
        __threadfence();
    }
}

// ---------------------------------------------------------------------------
__global__ __launch_bounds__(256) void diag_kernel(float* __restrict__ out,
                                                   int n, float code)
{
    for (int i = blockIdx.x * 256 + threadIdx.x; i < n; i += gridDim.x * 256)
        out[i] = (i == 0) ? code : 0.0f;
}

// ---------------------------------------------------------------------------
extern "C" void kernel_launch(void* const* d_in, const int* in_sizes, int n_in,
                              void* d_out, int out_size, void* d_ws, size_t ws_size,
                              hipStream_t stream)
{
    const float* x      = (const float*)d_in[0];
    const float* ctx    = (const float*)d_in[1];
    const float* W_in   = (const float*)d_in[2];
    const float* b_in   = (const float*)d_in[3];
    const float* Wih0   = (const float*)d_in[4];
    const float* Whh0   = (const float*)d_in[5];
    const float* bih0   = (const float*)d_in[6];
    const float* bhh0   = (const float*)d_in[7];
    const float* Wih1   = (const float*)d_in[8];
    const float* Whh1   = (const float*)d_in[9];
    const float* bih1   = (const float*)d_in[10];
    const float* bhh1   = (const float*)d_in[11];
    const float* W_out  = (const float*)d_in[12];
    const float* b_out  = (const float*)d_in[13];
    const float* W_gate = (const float*)d_in[14];
    const float* b_gate = (const float*)d_in[15];
    float* out = (float*)d_out;

    // ws layout (total = 146,931,712 B = proven fit):
    //   xg    [16384][3072] bf16 = 96 MiB
    //   hbuf  [16384][1024] bf16 = 32 MiB  (mixed -> h1 -> h2)
    //   wih0b [3072][1024]  bf16 =  6 MiB  (bar aliases first 4 KiB once dead)
    //   wih1b [3072][1024]  bf16 =  6 MiB
    //   gate  [32][1024]    f32  = 128 KiB
    const size_t XG  = (size_t)16384 * 3072 * 2;
    const size_t HB  = (size_t)16384 * 1024 * 2;
    const size_t WB  = (size_t)3072 * 1024 * 2;
    const size_t GT  = (size_t)32 * 1024 * 4;
    const size_t need = XG + HB + 2*WB + GT;

    if (ws_size < need) {
        diag_kernel<<<2048, 256, 0, stream>>>(out, out_size, (float)(ws_size >> 20));
        return;
    }

    char* ws = (char*)d_ws;
    unsigned short* xgb   = (unsigned short*)ws;
    unsigned short* hbuf  = (unsigned short*)(ws + XG);
    unsigned short* wih0b = (unsigned short*)(ws + XG + HB);
    unsigned short* wih1b = (unsigned short*)(ws + XG + HB + WB);
    float*          gate  = (float*)(ws + XG + HB + 2*WB);
    unsigned int*   bar   = (unsigned int*)wih0b;  // reused after wih0b is dead

    // weight conversions + gate GEMV
    f2b_kernel<<<3072, 256, 0, stream>>>(Wih0, wih0b, 3072 * 1024);
    f2b_kernel<<<3072, 256, 0, stream>>>(Wih1, wih1b, 3072 * 1024);
    gate_kernel<<<dim3(4, 32), 256, 0, stream>>>(ctx, W_gate, b_gate, gate);

    // mixed = tanh(x @ W_in^T + b_in + ctx[b]) -> hbuf (bf16)
    mfma_gemm<1, 1, 1><<<dim3(8, 128), 256, 0, stream>>>(
        x, W_in, b_in, ctx, nullptr, hbuf, 1024, 1024);

    // xg0 = mixed @ Wih0^T + bih0 -> xgb
    mfma_gemm<0, 0, 2><<<dim3(24, 128), 256, 0, stream>>>(
        hbuf, wih0b, bih0, nullptr, nullptr, xgb, 3072, 1024);

    // GRU layer 0 persistent scan (h1 overwrites hbuf)
    hipMemsetAsync(bar, 0, 4096, stream);
    gru_scan<<<64, 384, 0, stream>>>(Whh0, bhh0, xgb, hbuf, bar, 64);

    // xg1 = h1 @ Wih1^T + bih1 -> xgb
    mfma_gemm<0, 0, 2><<<dim3(24, 128), 256, 0, stream>>>(
        hbuf, wih1b, bih1, nullptr, nullptr, xgb, 3072, 1024);

    // GRU layer 1 persistent scan (h2 overwrites hbuf)
    hipMemsetAsync(bar, 0, 4096, stream);
    gru_scan<<<64, 384, 0, stream>>>(Whh1, bhh1, xgb, hbuf, bar, 64);

    // out = (h2 * (1+gate)) @ W_out^T + b_out -> f32
    mfma_gemm<2, 1, 0><<<dim3(8, 128), 256, 0, stream>>>(
        hbuf, W_out, b_out, nullptr, gate, out, 1024, 1024);
}

// Round 4
// 8660.437 us; speedup vs baseline: 2.5835x; 2.5835x over previous
//
#include <hip/hip_runtime.h>
#include <cstdint>
#include <cstddef>

#define SEQT  512
#define HID   1024
#define G3    3072

typedef __attribute__((ext_vector_type(8))) short bf16x8;
typedef __attribute__((ext_vector_type(8))) unsigned short u16x8;
typedef __attribute__((ext_vector_type(4))) float f32x4;

__device__ __forceinline__ float sigm(float x){ return 1.0f/(1.0f+expf(-x)); }
__device__ __forceinline__ float b2f(unsigned short s){ return __uint_as_float(((uint32_t)s)<<16); }
__device__ __forceinline__ unsigned short f2b(float f){
    uint32_t u=__float_as_uint(f);
    return (unsigned short)((u + 0x7FFFu + ((u>>16)&1u))>>16);
}

// ---------------------------------------------------------------------------
// MFMA GEMM: C[m][n] = epilogue( sum_k A[m][k]*W[n][k] )   (unchanged, proven)
// Tile 128x128, BK=64, 256 thr = 4 waves, each wave 64x64 (4x4 frags 16x16x32).
// ASRC: 0 = bf16 via global_load_lds; 1 = f32 reg-staged (convert);
//       2 = bf16 reg-staged with *(1+gate[m>>9][k]) fused.
// BSRC: 0 = bf16 via global_load_lds; 1 = f32 reg-staged.
// MODE: 0 = f32 out, +bias.  1 = bf16 out, tanh(+bias+ctx[m>>9][n]).
//       2 = bf16 out, +bias.
// ---------------------------------------------------------------------------
template<int ASRC, int BSRC, int MODE>
__global__ __launch_bounds__(256) void mfma_gemm(
    const void* __restrict__ Av, const void* __restrict__ Bv,
    const float* __restrict__ bias, const float* __restrict__ ctx,
    const float* __restrict__ gate, void* __restrict__ Cv,
    int N, int K)
{
    __shared__ __align__(16) unsigned short As[128*64];
    __shared__ __align__(16) unsigned short Bs[128*64];
    const int tid = threadIdx.x;
    const int lane = tid & 63;
    const int w = tid >> 6;
    const int wm = w & 1, wn = w >> 1;
    const int m0 = blockIdx.y * 128, n0 = blockIdx.x * 128;

    f32x4 acc[4][4];
#pragma unroll
    for (int i = 0; i < 4; i++)
#pragma unroll
        for (int j = 0; j < 4; j++) acc[i][j] = (f32x4){0.f,0.f,0.f,0.f};

    for (int kt = 0; kt < K; kt += 64) {
        __syncthreads();
        if (ASRC == 0) {
            const unsigned short* Ab = (const unsigned short*)Av;
#pragma unroll
            for (int c = 0; c < 4; c++) {
                const int chunk = w*4 + c;
                const int row = chunk*8 + (lane>>3);
                const unsigned short* src = Ab + (size_t)(m0+row)*K + kt + (lane&7)*8;
                __builtin_amdgcn_global_load_lds(
                    (const __attribute__((address_space(1))) void*)src,
                    (__attribute__((address_space(3))) void*)&As[chunk*512], 16, 0, 0);
            }
        } else if (ASRC == 1) {
            const float* Af = (const float*)Av;
#pragma unroll
            for (int p = 0; p < 4; p++) {
                const int q = p*256 + tid, row = q>>3, kc = q&7;
                const float* src = Af + (size_t)(m0+row)*K + kt + kc*8;
                float4 u = *(const float4*)src, v = *(const float4*)(src+4);
                __align__(16) unsigned short tmp[8] =
                    {f2b(u.x),f2b(u.y),f2b(u.z),f2b(u.w),f2b(v.x),f2b(v.y),f2b(v.z),f2b(v.w)};
                *(bf16x8*)&As[row*64 + kc*8] = *(const bf16x8*)tmp;
            }
        } else {
            const unsigned short* Ab = (const unsigned short*)Av;
#pragma unroll
            for (int p = 0; p < 4; p++) {
                const int q = p*256 + tid, row = q>>3, kc = q&7;
                const int b = (m0+row) >> 9;
                u16x8 hv = *(const u16x8*)(Ab + (size_t)(m0+row)*K + kt + kc*8);
                const float* gp = gate + (size_t)b*HID + kt + kc*8;
                float4 g0 = *(const float4*)gp, g1 = *(const float4*)(gp+4);
                const float gg[8] = {g0.x,g0.y,g0.z,g0.w,g1.x,g1.y,g1.z,g1.w};
                __align__(16) unsigned short tmp[8];
#pragma unroll
                for (int e = 0; e < 8; e++)
                    tmp[e] = f2b(b2f(hv[e]) * (1.0f + gg[e]));
                *(bf16x8*)&As[row*64 + kc*8] = *(const bf16x8*)tmp;
            }
        }
        if (BSRC == 0) {
            const unsigned short* Bb = (const unsigned short*)Bv;
#pragma unroll
            for (int c = 0; c < 4; c++) {
                const int chunk = w*4 + c;
                const int row = chunk*8 + (lane>>3);
                const unsigned short* src = Bb + (size_t)(n0+row)*K + kt + (lane&7)*8;
                __builtin_amdgcn_global_load_lds(
                    (const __attribute__((address_space(1))) void*)src,
                    (__attribute__((address_space(3))) void*)&Bs[chunk*512], 16, 0, 0);
            }
        } else {
            const float* Bf = (const float*)Bv;
#pragma unroll
            for (int p = 0; p < 4; p++) {
                const int q = p*256 + tid, row = q>>3, kc = q&7;
                const float* src = Bf + (size_t)(n0+row)*K + kt + kc*8;
                float4 u = *(const float4*)src, v = *(const float4*)(src+4);
                __align__(16) unsigned short tmp[8] =
                    {f2b(u.x),f2b(u.y),f2b(u.z),f2b(u.w),f2b(v.x),f2b(v.y),f2b(v.z),f2b(v.w)};
                *(bf16x8*)&Bs[row*64 + kc*8] = *(const bf16x8*)tmp;
            }
        }
        __syncthreads();
#pragma unroll
        for (int kg = 0; kg < 2; kg++) {
            bf16x8 af[4], bfr[4];
#pragma unroll
            for (int mi = 0; mi < 4; mi++)
                af[mi] = *(const bf16x8*)&As[(wm*64+mi*16+(lane&15))*64 + kg*32 + (lane>>4)*8];
#pragma unroll
            for (int ni = 0; ni < 4; ni++)
                bfr[ni] = *(const bf16x8*)&Bs[(wn*64+ni*16+(lane&15))*64 + kg*32 + (lane>>4)*8];
#pragma unroll
            for (int mi = 0; mi < 4; mi++)
#pragma unroll
                for (int ni = 0; ni < 4; ni++)
                    acc[mi][ni] = __builtin_amdgcn_mfma_f32_16x16x32_bf16(
                        af[mi], bfr[ni], acc[mi][ni], 0, 0, 0);
        }
    }

    const int cl = lane & 15, rg = lane >> 4;
    const int bct = m0 >> 9;
#pragma unroll
    for (int mi = 0; mi < 4; mi++) {
        const int rowb = m0 + wm*64 + mi*16 + rg*4;
#pragma unroll
        for (int ni = 0; ni < 4; ni++) {
            const int col = n0 + wn*64 + ni*16 + cl;
            const float bv = bias[col];
            const float cv = (MODE==1) ? ctx[(size_t)bct*HID + col] : 0.0f;
#pragma unroll
            for (int r = 0; r < 4; r++) {
                float val = acc[mi][ni][r] + bv;
                if (MODE==1) val = tanhf(val + cv);
                const size_t off = (size_t)(rowb+r)*N + col;
                if (MODE==0) ((float*)Cv)[off] = val;
                else ((unsigned short*)Cv)[off] = f2b(val);
            }
        }
    }
}

// ---------------------------------------------------------------------------
__global__ __launch_bounds__(256) void gate_kernel(
    const float* __restrict__ ctx, const float* __restrict__ Wg,
    const float* __restrict__ bg, float* __restrict__ gate)
{
    const int j = blockIdx.x * 256 + threadIdx.x;
    const int b = blockIdx.y;
    const float4* cp = (const float4*)(ctx + (size_t)b * HID);
    const float4* wp = (const float4*)(Wg + (size_t)j * HID);
    float acc = 0.0f;
#pragma unroll 4
    for (int k = 0; k < HID / 4; k++) {
        float4 c = cp[k], w = wp[k];
        acc += c.x * w.x + c.y * w.y + c.z * w.z + c.w * w.w;
    }
    gate[(size_t)b * HID + j] = sigm(acc + bg[j]);
}

// ---------------------------------------------------------------------------
__global__ __launch_bounds__(256) void f2b_kernel(
    const float* __restrict__ in, unsigned short* __restrict__ out, int n)
{
    const int i = (blockIdx.x * 256 + threadIdx.x) * 4;
    if (i < n) {
        float4 v = *(const float4*)(in + i);
        unsigned short s[4] = {f2b(v.x), f2b(v.y), f2b(v.z), f2b(v.w)};
        *(short4*)(out + i) = *(short4*)s;
    }
}

// ---------------------------------------------------------------------------
// Persistent GRU layer scan — fence-free cross-XCD handoff.
// 64 blocks x 384 thr (6 waves). Block owns 16 j-columns; Whh slice in LDS.
// h stores: packed u32 agent-scope atomic (write-through to LLC, no dirty L2)
// Barrier: per-wave vmcnt(0) -> __syncthreads -> tid0 relaxed agent
// fetch_add + spin (no __threadfence / L2 writeback anywhere).
// ---------------------------------------------------------------------------
__global__ __launch_bounds__(384, 1) void gru_scan(
    const float* __restrict__ Whh, const float* __restrict__ bhh,
    const unsigned short* __restrict__ xg, unsigned short* __restrict__ hbuf,
    unsigned int* __restrict__ bar, int nblocks)
{
    __shared__ __align__(16) unsigned short wlds[48*1032];
    __shared__ float sc[3][32][17];
    const int tid = threadIdx.x;
    const int lane = tid & 63;
    const int w = tid >> 6;
    const int j0 = blockIdx.x * 16;
    const int mh = w & 1, g = w >> 1;
    const int cl = lane & 15, kq = lane >> 4;

    // stage Whh slice f32 -> bf16 LDS: row rr=g16+jr <- Whh[g*1024 + j0+jr]
    for (int i = tid; i < 48*128; i += 384) {
        const int rr = i >> 7, kc = i & 127;
        const int grow = (rr>>4)*1024 + j0 + (rr&15);
        const float* src = Whh + (size_t)grow*1024 + kc*8;
        float4 u = *(const float4*)src, v = *(const float4*)(src+4);
        __align__(16) unsigned short tmp[8] =
            {f2b(u.x),f2b(u.y),f2b(u.z),f2b(u.w),f2b(v.x),f2b(v.y),f2b(v.z),f2b(v.w)};
        *(bf16x8*)&wlds[rr*1032 + kc*8] = *(const bf16x8*)tmp;
    }
    __syncthreads();

    const unsigned short* wrow = &wlds[(g*16+cl)*1032 + kq*8];

    // finalize-thread identity (tid<256): batch fb, column pair j0+fj
    const int fb = tid >> 3;
    const int fj = (tid & 7) * 2;
    float hp0 = 0.f, hp1 = 0.f;          // register-resident h[t-1] (own pair)
    float br0=0,br1=0,bz0=0,bz1=0,bn0=0,bn1=0;
    if (tid < 256) {
        br0 = bhh[j0+fj];          br1 = bhh[j0+fj+1];
        bz0 = bhh[HID+j0+fj];      bz1 = bhh[HID+j0+fj+1];
        bn0 = bhh[2*HID+j0+fj];    bn1 = bhh[2*HID+j0+fj+1];
    }

    for (int t = 0; t < SEQT; t++) {
        // issue xg[t] loads early (overlap with h loads)
        uint32_t xr2=0, xz2=0, xn2=0;
        if (tid < 256) {
            const unsigned short* xp = xg + ((size_t)fb*SEQT + t)*G3 + j0 + fj;
            xr2 = *(const uint32_t*)(xp);
            xz2 = *(const uint32_t*)(xp + 1024);
            xn2 = *(const uint32_t*)(xp + 2048);
        }

        f32x4 a0 = {0.f,0.f,0.f,0.f}, a1 = a0, a2 = a0, a3 = a0;
        if (t > 0) {
            const unsigned short* hrow =
                hbuf + ((size_t)(mh*16+cl)*SEQT + (t-1))*HID + kq*8;
#pragma unroll
            for (int kg = 0; kg < 32; kg += 4) {
                bf16x8 h0 = *(const bf16x8*)(hrow + (size_t)(kg+0)*32);
                bf16x8 w0 = *(const bf16x8*)(wrow + (size_t)(kg+0)*32);
                a0 = __builtin_amdgcn_mfma_f32_16x16x32_bf16(h0, w0, a0, 0,0,0);
                bf16x8 h1 = *(const bf16x8*)(hrow + (size_t)(kg+1)*32);
                bf16x8 w1 = *(const bf16x8*)(wrow + (size_t)(kg+1)*32);
                a1 = __builtin_amdgcn_mfma_f32_16x16x32_bf16(h1, w1, a1, 0,0,0);
                bf16x8 h2 = *(const bf16x8*)(hrow + (size_t)(kg+2)*32);
                bf16x8 w2 = *(const bf16x8*)(wrow + (size_t)(kg+2)*32);
                a2 = __builtin_amdgcn_mfma_f32_16x16x32_bf16(h2, w2, a2, 0,0,0);
                bf16x8 h3 = *(const bf16x8*)(hrow + (size_t)(kg+3)*32);
                bf16x8 w3 = *(const bf16x8*)(wrow + (size_t)(kg+3)*32);
                a3 = __builtin_amdgcn_mfma_f32_16x16x32_bf16(h3, w3, a3, 0,0,0);
            }
        }
        f32x4 av = (a0 + a1) + (a2 + a3);
#pragma unroll
        for (int r = 0; r < 4; r++)
            sc[g][mh*16 + kq*4 + r][cl] = av[r];
        __syncthreads();

        if (tid < 256) {
            const float r0 = sigm(b2f((unsigned short)(xr2 & 0xFFFF))      + sc[0][fb][fj]   + br0);
            const float r1 = sigm(b2f((unsigned short)(xr2 >> 16))         + sc[0][fb][fj+1] + br1);
            const float z0 = sigm(b2f((unsigned short)(xz2 & 0xFFFF))      + sc[1][fb][fj]   + bz0);
            const float z1 = sigm(b2f((unsigned short)(xz2 >> 16))         + sc[1][fb][fj+1] + bz1);
            const float n0 = tanhf(b2f((unsigned short)(xn2 & 0xFFFF)) + r0*(sc[2][fb][fj]   + bn0));
            const float n1 = tanhf(b2f((unsigned short)(xn2 >> 16))    + r1*(sc[2][fb][fj+1] + bn1));
            const float h0 = (1.0f - z0)*n0 + z0*hp0;
            const float h1 = (1.0f - z1)*n1 + z1*hp1;
            hp0 = h0; hp1 = h1;
            const uint32_t hv = (uint32_t)f2b(h0) | ((uint32_t)f2b(h1) << 16);
            uint32_t* dst = (uint32_t*)(hbuf + ((size_t)fb*SEQT + t)*HID + j0 + fj);
            __hip_atomic_store(dst, hv, __ATOMIC_RELAXED, __HIP_MEMORY_SCOPE_AGENT);
        }
        // per-wave: ensure our write-through stores are acked at the
        // coherence point before signalling arrival
        asm volatile("s_waitcnt vmcnt(0)" ::: "memory");
        __syncthreads();
        if (tid == 0) {
            __hip_atomic_fetch_add(bar, 1u, __ATOMIC_RELAXED, __HIP_MEMORY_SCOPE_AGENT);
            const unsigned int target = (unsigned int)nblocks * (unsigned int)(t+1);
            while (__hip_atomic_load(bar, __ATOMIC_RELAXED, __HIP_MEMORY_SCOPE_AGENT) < target)
                __builtin_amdgcn_s_sleep(1);
        }
        __syncthreads();
    }
}

// ---------------------------------------------------------------------------
__global__ __launch_bounds__(256) void diag_kernel(float* __restrict__ out,
                                                   int n, float code)
{
    for (int i = blockIdx.x * 256 + threadIdx.x; i < n; i += gridDim.x * 256)
        out[i] = (i == 0) ? code : 0.0f;
}

// ---------------------------------------------------------------------------
extern "C" void kernel_launch(void* const* d_in, const int* in_sizes, int n_in,
                              void* d_out, int out_size, void* d_ws, size_t ws_size,
                              hipStream_t stream)
{
    const float* x      = (const float*)d_in[0];
    const float* ctx    = (const float*)d_in[1];
    const float* W_in   = (const float*)d_in[2];
    const float* b_in   = (const float*)d_in[3];
    const float* Wih0   = (const float*)d_in[4];
    const float* Whh0   = (const float*)d_in[5];
    const float* bih0   = (const float*)d_in[6];
    const float* bhh0   = (const float*)d_in[7];
    const float* Wih1   = (const float*)d_in[8];
    const float* Whh1   = (const float*)d_in[9];
    const float* bih1   = (const float*)d_in[10];
    const float* bhh1   = (const float*)d_in[11];
    const float* W_out  = (const float*)d_in[12];
    const float* b_out  = (const float*)d_in[13];
    const float* W_gate = (const float*)d_in[14];
    const float* b_gate = (const float*)d_in[15];
    float* out = (float*)d_out;

    // ws layout:
    //   xg    [16384][3072] bf16 = 96 MiB
    //   hbuf  [16384][1024] bf16 = 32 MiB  (mixed -> h1 -> h2)
    //   wih0b, wih1b [3072][1024] bf16 = 6 MiB each
    //   gate  [32][1024] f32 = 128 KiB
    //   bar   dedicated 4 KiB (bar[0]: scan1, bar[32]: scan2)
    const size_t XG  = (size_t)16384 * 3072 * 2;
    const size_t HB  = (size_t)16384 * 1024 * 2;
    const size_t WB  = (size_t)3072 * 1024 * 2;
    const size_t GT  = (size_t)32 * 1024 * 4;
    const size_t need = XG + HB + 2*WB + GT + 4096;

    if (ws_size < need) {
        diag_kernel<<<2048, 256, 0, stream>>>(out, out_size, (float)(ws_size >> 20));
        return;
    }

    char* ws = (char*)d_ws;
    unsigned short* xgb   = (unsigned short*)ws;
    unsigned short* hbuf  = (unsigned short*)(ws + XG);
    unsigned short* wih0b = (unsigned short*)(ws + XG + HB);
    unsigned short* wih1b = (unsigned short*)(ws + XG + HB + WB);
    float*          gate  = (float*)(ws + XG + HB + 2*WB);
    unsigned int*   bar   = (unsigned int*)(ws + XG + HB + 2*WB + GT);

    f2b_kernel<<<3072, 256, 0, stream>>>(Wih0, wih0b, 3072 * 1024);
    f2b_kernel<<<3072, 256, 0, stream>>>(Wih1, wih1b, 3072 * 1024);
    gate_kernel<<<dim3(4, 32), 256, 0, stream>>>(ctx, W_gate, b_gate, gate);
    hipMemsetAsync(bar, 0, 256, stream);

    // mixed = tanh(x @ W_in^T + b_in + ctx[b]) -> hbuf (bf16)
    mfma_gemm<1, 1, 1><<<dim3(8, 128), 256, 0, stream>>>(
        x, W_in, b_in, ctx, nullptr, hbuf, 1024, 1024);

    // xg0 = mixed @ Wih0^T + bih0 -> xgb
    mfma_gemm<0, 0, 2><<<dim3(24, 128), 256, 0, stream>>>(
        hbuf, wih0b, bih0, nullptr, nullptr, xgb, 3072, 1024);

    // GRU layer 0 persistent scan (h1 overwrites hbuf)
    gru_scan<<<64, 384, 0, stream>>>(Whh0, bhh0, xgb, hbuf, bar, 64);

    // xg1 = h1 @ Wih1^T + bih1 -> xgb
    mfma_gemm<0, 0, 2><<<dim3(24, 128), 256, 0, stream>>>(
        hbuf, wih1b, bih1, nullptr, nullptr, xgb, 3072, 1024);

    // GRU layer 1 persistent scan (h2 overwrites hbuf)
    gru_scan<<<64, 384, 0, stream>>>(Whh1, bhh1, xgb, hbuf, bar + 32, 64);

    // out = (h2 * (1+gate)) @ W_out^T + b_out -> f32
    mfma_gemm<2, 1, 0><<<dim3(8, 128), 256, 0, stream>>>(
        hbuf, W_out, b_out, nullptr, gate, out, 1024, 1024);
}

// Round 5
// 8028.477 us; speedup vs baseline: 2.7869x; 1.0787x over previous
//
#include <hip/hip_runtime.h>
#include <cstdint>
#include <cstddef>

#define SEQT  512
#define HID   1024
#define G3    3072

typedef __attribute__((ext_vector_type(8))) short bf16x8;
typedef __attribute__((ext_vector_type(8))) unsigned short u16x8;
typedef __attribute__((ext_vector_type(4))) float f32x4;

__device__ __forceinline__ float sigm(float x){ return 1.0f/(1.0f+expf(-x)); }
__device__ __forceinline__ float b2f(unsigned short s){ return __uint_as_float(((uint32_t)s)<<16); }
__device__ __forceinline__ unsigned short f2b(float f){
    uint32_t u=__float_as_uint(f);
    return (unsigned short)((u + 0x7FFFu + ((u>>16)&1u))>>16);
}

// ---------------------------------------------------------------------------
// MFMA GEMM: C[m][n] = epilogue( sum_k A[m][k]*W[n][k] )   (unchanged, proven)
// Tile 128x128, BK=64, 256 thr = 4 waves, each wave 64x64 (4x4 frags 16x16x32).
// ASRC: 0 = bf16 via global_load_lds; 1 = f32 reg-staged (convert);
//       2 = bf16 reg-staged with *(1+gate[m>>9][k]) fused.
// BSRC: 0 = bf16 via global_load_lds; 1 = f32 reg-staged.
// MODE: 0 = f32 out, +bias.  1 = bf16 out, tanh(+bias+ctx[m>>9][n]).
//       2 = bf16 out, +bias.
// ---------------------------------------------------------------------------
template<int ASRC, int BSRC, int MODE>
__global__ __launch_bounds__(256) void mfma_gemm(
    const void* __restrict__ Av, const void* __restrict__ Bv,
    const float* __restrict__ bias, const float* __restrict__ ctx,
    const float* __restrict__ gate, void* __restrict__ Cv,
    int N, int K)
{
    __shared__ __align__(16) unsigned short As[128*64];
    __shared__ __align__(16) unsigned short Bs[128*64];
    const int tid = threadIdx.x;
    const int lane = tid & 63;
    const int w = tid >> 6;
    const int wm = w & 1, wn = w >> 1;
    const int m0 = blockIdx.y * 128, n0 = blockIdx.x * 128;

    f32x4 acc[4][4];
#pragma unroll
    for (int i = 0; i < 4; i++)
#pragma unroll
        for (int j = 0; j < 4; j++) acc[i][j] = (f32x4){0.f,0.f,0.f,0.f};

    for (int kt = 0; kt < K; kt += 64) {
        __syncthreads();
        if (ASRC == 0) {
            const unsigned short* Ab = (const unsigned short*)Av;
#pragma unroll
            for (int c = 0; c < 4; c++) {
                const int chunk = w*4 + c;
                const int row = chunk*8 + (lane>>3);
                const unsigned short* src = Ab + (size_t)(m0+row)*K + kt + (lane&7)*8;
                __builtin_amdgcn_global_load_lds(
                    (const __attribute__((address_space(1))) void*)src,
                    (__attribute__((address_space(3))) void*)&As[chunk*512], 16, 0, 0);
            }
        } else if (ASRC == 1) {
            const float* Af = (const float*)Av;
#pragma unroll
            for (int p = 0; p < 4; p++) {
                const int q = p*256 + tid, row = q>>3, kc = q&7;
                const float* src = Af + (size_t)(m0+row)*K + kt + kc*8;
                float4 u = *(const float4*)src, v = *(const float4*)(src+4);
                __align__(16) unsigned short tmp[8] =
                    {f2b(u.x),f2b(u.y),f2b(u.z),f2b(u.w),f2b(v.x),f2b(v.y),f2b(v.z),f2b(v.w)};
                *(bf16x8*)&As[row*64 + kc*8] = *(const bf16x8*)tmp;
            }
        } else {
            const unsigned short* Ab = (const unsigned short*)Av;
#pragma unroll
            for (int p = 0; p < 4; p++) {
                const int q = p*256 + tid, row = q>>3, kc = q&7;
                const int b = (m0+row) >> 9;
                u16x8 hv = *(const u16x8*)(Ab + (size_t)(m0+row)*K + kt + kc*8);
                const float* gp = gate + (size_t)b*HID + kt + kc*8;
                float4 g0 = *(const float4*)gp, g1 = *(const float4*)(gp+4);
                const float gg[8] = {g0.x,g0.y,g0.z,g0.w,g1.x,g1.y,g1.z,g1.w};
                __align__(16) unsigned short tmp[8];
#pragma unroll
                for (int e = 0; e < 8; e++)
                    tmp[e] = f2b(b2f(hv[e]) * (1.0f + gg[e]));
                *(bf16x8*)&As[row*64 + kc*8] = *(const bf16x8*)tmp;
            }
        }
        if (BSRC == 0) {
            const unsigned short* Bb = (const unsigned short*)Bv;
#pragma unroll
            for (int c = 0; c < 4; c++) {
                const int chunk = w*4 + c;
                const int row = chunk*8 + (lane>>3);
                const unsigned short* src = Bb + (size_t)(n0+row)*K + kt + (lane&7)*8;
                __builtin_amdgcn_global_load_lds(
                    (const __attribute__((address_space(1))) void*)src,
                    (__attribute__((address_space(3))) void*)&Bs[chunk*512], 16, 0, 0);
            }
        } else {
            const float* Bf = (const float*)Bv;
#pragma unroll
            for (int p = 0; p < 4; p++) {
                const int q = p*256 + tid, row = q>>3, kc = q&7;
                const float* src = Bf + (size_t)(n0+row)*K + kt + kc*8;
                float4 u = *(const float4*)src, v = *(const float4*)(src+4);
                __align__(16) unsigned short tmp[8] =
                    {f2b(u.x),f2b(u.y),f2b(u.z),f2b(u.w),f2b(v.x),f2b(v.y),f2b(v.z),f2b(v.w)};
                *(bf16x8*)&Bs[row*64 + kc*8] = *(const bf16x8*)tmp;
            }
        }
        __syncthreads();
#pragma unroll
        for (int kg = 0; kg < 2; kg++) {
            bf16x8 af[4], bfr[4];
#pragma unroll
            for (int mi = 0; mi < 4; mi++)
                af[mi] = *(const bf16x8*)&As[(wm*64+mi*16+(lane&15))*64 + kg*32 + (lane>>4)*8];
#pragma unroll
            for (int ni = 0; ni < 4; ni++)
                bfr[ni] = *(const bf16x8*)&Bs[(wn*64+ni*16+(lane&15))*64 + kg*32 + (lane>>4)*8];
#pragma unroll
            for (int mi = 0; mi < 4; mi++)
#pragma unroll
                for (int ni = 0; ni < 4; ni++)
                    acc[mi][ni] = __builtin_amdgcn_mfma_f32_16x16x32_bf16(
                        af[mi], bfr[ni], acc[mi][ni], 0, 0, 0);
        }
    }

    const int cl = lane & 15, rg = lane >> 4;
    const int bct = m0 >> 9;
#pragma unroll
    for (int mi = 0; mi < 4; mi++) {
        const int rowb = m0 + wm*64 + mi*16 + rg*4;
#pragma unroll
        for (int ni = 0; ni < 4; ni++) {
            const int col = n0 + wn*64 + ni*16 + cl;
            const float bv = bias[col];
            const float cv = (MODE==1) ? ctx[(size_t)bct*HID + col] : 0.0f;
#pragma unroll
            for (int r = 0; r < 4; r++) {
                float val = acc[mi][ni][r] + bv;
                if (MODE==1) val = tanhf(val + cv);
                const size_t off = (size_t)(rowb+r)*N + col;
                if (MODE==0) ((float*)Cv)[off] = val;
                else ((unsigned short*)Cv)[off] = f2b(val);
            }
        }
    }
}

// ---------------------------------------------------------------------------
__global__ __launch_bounds__(256) void gate_kernel(
    const float* __restrict__ ctx, const float* __restrict__ Wg,
    const float* __restrict__ bg, float* __restrict__ gate)
{
    const int j = blockIdx.x * 256 + threadIdx.x;
    const int b = blockIdx.y;
    const float4* cp = (const float4*)(ctx + (size_t)b * HID);
    const float4* wp = (const float4*)(Wg + (size_t)j * HID);
    float acc = 0.0f;
#pragma unroll 4
    for (int k = 0; k < HID / 4; k++) {
        float4 c = cp[k], w = wp[k];
        acc += c.x * w.x + c.y * w.y + c.z * w.z + c.w * w.w;
    }
    gate[(size_t)b * HID + j] = sigm(acc + bg[j]);
}

// ---------------------------------------------------------------------------
__global__ __launch_bounds__(256) void f2b_kernel(
    const float* __restrict__ in, unsigned short* __restrict__ out, int n)
{
    const int i = (blockIdx.x * 256 + threadIdx.x) * 4;
    if (i < n) {
        float4 v = *(const float4*)(in + i);
        unsigned short s[4] = {f2b(v.x), f2b(v.y), f2b(v.z), f2b(v.w)};
        *(short4*)(out + i) = *(short4*)s;
    }
}

// ---------------------------------------------------------------------------
// Persistent GRU layer scan — distributed-flag rendezvous (no RMW, no sleep).
// 64 blocks x 384 thr (6 waves). Block owns 16 j-columns; Whh slice in LDS.
// h stores: packed u32 agent-scope store (write-through to LLC).
// Arrival: per-wave vmcnt(0) -> __syncthreads -> tid0 stores flag[bid]=t+1.
// Wait (top of step t>0): wave 0 lanes poll flag[lane] >= t (64 parallel
// loads, one per producer block), divergent exit, then __syncthreads.
// flags stride 16 u32 = 64 B (distinct lines for writes, read-shared polls).
// ---------------------------------------------------------------------------
__global__ __launch_bounds__(384, 1) void gru_scan(
    const float* __restrict__ Whh, const float* __restrict__ bhh,
    const unsigned short* __restrict__ xg, unsigned short* __restrict__ hbuf,
    unsigned int* __restrict__ flags)
{
    __shared__ __align__(16) unsigned short wlds[48*1032];
    __shared__ float sc[3][32][17];
    const int tid = threadIdx.x;
    const int lane = tid & 63;
    const int w = tid >> 6;
    const int bid = blockIdx.x;
    const int j0 = bid * 16;
    const int mh = w & 1, g = w >> 1;
    const int cl = lane & 15, kq = lane >> 4;

    // stage Whh slice f32 -> bf16 LDS: row rr=g*16+jr <- Whh[g*1024 + j0+jr]
    for (int i = tid; i < 48*128; i += 384) {
        const int rr = i >> 7, kc = i & 127;
        const int grow = (rr>>4)*1024 + j0 + (rr&15);
        const float* src = Whh + (size_t)grow*1024 + kc*8;
        float4 u = *(const float4*)src, v = *(const float4*)(src+4);
        __align__(16) unsigned short tmp[8] =
            {f2b(u.x),f2b(u.y),f2b(u.z),f2b(u.w),f2b(v.x),f2b(v.y),f2b(v.z),f2b(v.w)};
        *(bf16x8*)&wlds[rr*1032 + kc*8] = *(const bf16x8*)tmp;
    }
    __syncthreads();

    const unsigned short* wrow = &wlds[(g*16+cl)*1032 + kq*8];

    // finalize-thread identity (tid<256): batch fb, column pair j0+fj
    const int fb = tid >> 3;
    const int fj = (tid & 7) * 2;
    float hp0 = 0.f, hp1 = 0.f;          // register-resident h[t-1] (own pair)
    float br0=0,br1=0,bz0=0,bz1=0,bn0=0,bn1=0;
    if (tid < 256) {
        br0 = bhh[j0+fj];          br1 = bhh[j0+fj+1];
        bz0 = bhh[HID+j0+fj];      bz1 = bhh[HID+j0+fj+1];
        bn0 = bhh[2*HID+j0+fj];    bn1 = bhh[2*HID+j0+fj+1];
    }

    for (int t = 0; t < SEQT; t++) {
        // issue xg[t] loads before the wait (HBM latency hides under poll)
        uint32_t xr2=0, xz2=0, xn2=0;
        if (tid < 256) {
            const unsigned short* xp = xg + ((size_t)fb*SEQT + t)*G3 + j0 + fj;
            xr2 = *(const uint32_t*)(xp);
            xz2 = *(const uint32_t*)(xp + 1024);
            xn2 = *(const uint32_t*)(xp + 2048);
        }

        // wait until every block has published h[t-1]
        if (t > 0) {
            if (w == 0) {
                const unsigned int tgt = (unsigned int)t;
                while (__hip_atomic_load(&flags[lane*16], __ATOMIC_RELAXED,
                                         __HIP_MEMORY_SCOPE_AGENT) < tgt) {}
            }
            __syncthreads();
        }

        f32x4 a0 = {0.f,0.f,0.f,0.f}, a1 = a0, a2 = a0, a3 = a0;
        if (t > 0) {
            const unsigned short* hrow =
                hbuf + ((size_t)(mh*16+cl)*SEQT + (t-1))*HID + kq*8;
#pragma unroll
            for (int kg = 0; kg < 32; kg += 4) {
                bf16x8 h0 = *(const bf16x8*)(hrow + (size_t)(kg+0)*32);
                bf16x8 w0 = *(const bf16x8*)(wrow + (size_t)(kg+0)*32);
                a0 = __builtin_amdgcn_mfma_f32_16x16x32_bf16(h0, w0, a0, 0,0,0);
                bf16x8 h1 = *(const bf16x8*)(hrow + (size_t)(kg+1)*32);
                bf16x8 w1 = *(const bf16x8*)(wrow + (size_t)(kg+1)*32);
                a1 = __builtin_amdgcn_mfma_f32_16x16x32_bf16(h1, w1, a1, 0,0,0);
                bf16x8 h2 = *(const bf16x8*)(hrow + (size_t)(kg+2)*32);
                bf16x8 w2 = *(const bf16x8*)(wrow + (size_t)(kg+2)*32);
                a2 = __builtin_amdgcn_mfma_f32_16x16x32_bf16(h2, w2, a2, 0,0,0);
                bf16x8 h3 = *(const bf16x8*)(hrow + (size_t)(kg+3)*32);
                bf16x8 w3 = *(const bf16x8*)(wrow + (size_t)(kg+3)*32);
                a3 = __builtin_amdgcn_mfma_f32_16x16x32_bf16(h3, w3, a3, 0,0,0);
            }
        }
        f32x4 av = (a0 + a1) + (a2 + a3);
#pragma unroll
        for (int r = 0; r < 4; r++)
            sc[g][mh*16 + kq*4 + r][cl] = av[r];
        __syncthreads();

        if (tid < 256) {
            const float r0 = sigm(b2f((unsigned short)(xr2 & 0xFFFF))      + sc[0][fb][fj]   + br0);
            const float r1 = sigm(b2f((unsigned short)(xr2 >> 16))         + sc[0][fb][fj+1] + br1);
            const float z0 = sigm(b2f((unsigned short)(xz2 & 0xFFFF))      + sc[1][fb][fj]   + bz0);
            const float z1 = sigm(b2f((unsigned short)(xz2 >> 16))         + sc[1][fb][fj+1] + bz1);
            const float n0 = tanhf(b2f((unsigned short)(xn2 & 0xFFFF)) + r0*(sc[2][fb][fj]   + bn0));
            const float n1 = tanhf(b2f((unsigned short)(xn2 >> 16))    + r1*(sc[2][fb][fj+1] + bn1));
            const float h0 = (1.0f - z0)*n0 + z0*hp0;
            const float h1 = (1.0f - z1)*n1 + z1*hp1;
            hp0 = h0; hp1 = h1;
            const uint32_t hv = (uint32_t)f2b(h0) | ((uint32_t)f2b(h1) << 16);
            uint32_t* dst = (uint32_t*)(hbuf + ((size_t)fb*SEQT + t)*HID + j0 + fj);
            __hip_atomic_store(dst, hv, __ATOMIC_RELAXED, __HIP_MEMORY_SCOPE_AGENT);
        }
        // each wave: own write-through stores acked at coherence point
        asm volatile("s_waitcnt vmcnt(0)" ::: "memory");
        __syncthreads();
        // publish arrival (plain agent-scope store, own 64B line, no RMW)
        if (tid == 0)
            __hip_atomic_store(&flags[bid*16], (unsigned int)(t+1),
                               __ATOMIC_RELAXED, __HIP_MEMORY_SCOPE_AGENT);
    }
}

// ---------------------------------------------------------------------------
__global__ __launch_bounds__(256) void diag_kernel(float* __restrict__ out,
                                                   int n, float code)
{
    for (int i = blockIdx.x * 256 + threadIdx.x; i < n; i += gridDim.x * 256)
        out[i] = (i == 0) ? code : 0.0f;
}

// ---------------------------------------------------------------------------
extern "C" void kernel_launch(void* const* d_in, const int* in_sizes, int n_in,
                              void* d_out, int out_size, void* d_ws, size_t ws_size,
                              hipStream_t stream)
{
    const float* x      = (const float*)d_in[0];
    const float* ctx    = (const float*)d_in[1];
    const float* W_in   = (const float*)d_in[2];
    const float* b_in   = (const float*)d_in[3];
    const float* Wih0   = (const float*)d_in[4];
    const float* Whh0   = (const float*)d_in[5];
    const float* bih0   = (const float*)d_in[6];
    const float* bhh0   = (const float*)d_in[7];
    const float* Wih1   = (const float*)d_in[8];
    const float* Whh1   = (const float*)d_in[9];
    const float* bih1   = (const float*)d_in[10];
    const float* bhh1   = (const float*)d_in[11];
    const float* W_out  = (const float*)d_in[12];
    const float* b_out  = (const float*)d_in[13];
    const float* W_gate = (const float*)d_in[14];
    const float* b_gate = (const float*)d_in[15];
    float* out = (float*)d_out;

    // ws layout:
    //   xg    [16384][3072] bf16 = 96 MiB
    //   hbuf  [16384][1024] bf16 = 32 MiB  (mixed -> h1 -> h2)
    //   wih0b, wih1b [3072][1024] bf16 = 6 MiB each
    //   gate  [32][1024] f32 = 128 KiB
    //   flags 16 KiB (scan0 at +0, scan1 at +8 KiB; stride 64 B per block)
    const size_t XG  = (size_t)16384 * 3072 * 2;
    const size_t HB  = (size_t)16384 * 1024 * 2;
    const size_t WB  = (size_t)3072 * 1024 * 2;
    const size_t GT  = (size_t)32 * 1024 * 4;
    const size_t need = XG + HB + 2*WB + GT + 16384;

    if (ws_size < need) {
        diag_kernel<<<2048, 256, 0, stream>>>(out, out_size, (float)(ws_size >> 20));
        return;
    }

    char* ws = (char*)d_ws;
    unsigned short* xgb   = (unsigned short*)ws;
    unsigned short* hbuf  = (unsigned short*)(ws + XG);
    unsigned short* wih0b = (unsigned short*)(ws + XG + HB);
    unsigned short* wih1b = (unsigned short*)(ws + XG + HB + WB);
    float*          gate  = (float*)(ws + XG + HB + 2*WB);
    unsigned int*   flags = (unsigned int*)(ws + XG + HB + 2*WB + GT);

    f2b_kernel<<<3072, 256, 0, stream>>>(Wih0, wih0b, 3072 * 1024);
    f2b_kernel<<<3072, 256, 0, stream>>>(Wih1, wih1b, 3072 * 1024);
    gate_kernel<<<dim3(4, 32), 256, 0, stream>>>(ctx, W_gate, b_gate, gate);
    hipMemsetAsync(flags, 0, 16384, stream);

    // mixed = tanh(x @ W_in^T + b_in + ctx[b]) -> hbuf (bf16)
    mfma_gemm<1, 1, 1><<<dim3(8, 128), 256, 0, stream>>>(
        x, W_in, b_in, ctx, nullptr, hbuf, 1024, 1024);

    // xg0 = mixed @ Wih0^T + bih0 -> xgb
    mfma_gemm<0, 0, 2><<<dim3(24, 128), 256, 0, stream>>>(
        hbuf, wih0b, bih0, nullptr, nullptr, xgb, 3072, 1024);

    // GRU layer 0 persistent scan (h1 overwrites hbuf)
    gru_scan<<<64, 384, 0, stream>>>(Whh0, bhh0, xgb, hbuf, flags);

    // xg1 = h1 @ Wih1^T + bih1 -> xgb
    mfma_gemm<0, 0, 2><<<dim3(24, 128), 256, 0, stream>>>(
        hbuf, wih1b, bih1, nullptr, nullptr, xgb, 3072, 1024);

    // GRU layer 1 persistent scan (h2 overwrites hbuf)
    gru_scan<<<64, 384, 0, stream>>>(Whh1, bhh1, xgb, hbuf, flags + 2048);

    // out = (h2 * (1+gate)) @ W_out^T + b_out -> f32
    mfma_gemm<2, 1, 0><<<dim3(8, 128), 256, 0, stream>>>(
        hbuf, W_out, b_out, nullptr, gate, out, 1024, 1024);
}